// Round 1
// baseline (248.274 us; speedup 1.0000x reference)
//
#include <hip/hip_runtime.h>

// Problem: B=8, S=2048, IN=1024, H=1024
//   q  = vec @ wq_w^T + wq_b            [B,S,H]
//   ret= relu(q_b^T q_b) per batch      [B,H,H]   (never materialized in HBM)
//   out= ret @ lin_w + lin_b            [B,H]
//
// Kernel A: qT[h][b*S+s] = sum_i wq_w[h][i]*vec[b,s,i] + wq_b[h]   (bf16, in d_ws)
// Kernel B: per batch, C[x][y] = sum_s qT[x][..s] qT[y][..s]; epilogue fuses
//           relu + dot with lin_w, atomicAdd into out.

#define BM 128
#define BN 128
#define BK 32

typedef short     bf16x8 __attribute__((ext_vector_type(8)));
typedef unsigned short u16x8 __attribute__((ext_vector_type(8)));
typedef float     f32x4 __attribute__((ext_vector_type(4)));

__device__ inline unsigned short f2bf(float f) {
  unsigned int u = __float_as_uint(f);
  u += 0x7fffu + ((u >> 16) & 1u);   // RNE
  return (unsigned short)(u >> 16);
}

__device__ inline u16x8 pack8(float4 a, float4 b) {
  u16x8 r;
  r[0] = f2bf(a.x); r[1] = f2bf(a.y); r[2] = f2bf(a.z); r[3] = f2bf(a.w);
  r[4] = f2bf(b.x); r[5] = f2bf(b.y); r[6] = f2bf(b.z); r[7] = f2bf(b.w);
  return r;
}

__device__ inline void async16(unsigned short* lds, const unsigned short* g) {
  __builtin_amdgcn_global_load_lds(
      (const __attribute__((address_space(1))) void*)g,
      (__attribute__((address_space(3))) void*)lds,
      16, 0, 0);
}

__global__ void init_out(float* __restrict__ out, const float* __restrict__ lin_b) {
  int i = blockIdx.x * 256 + threadIdx.x;
  if (i < 8192) out[i] = lin_b[0];
}

// ---------------- Kernel A: qT = wq_w * vec^T + bias ----------------
// M = 1024 (h), N = 16384 (b*s), K = 1024 (in). A=wq_w [1024,1024] fp32 (K-contig),
// B=vec [16384,1024] fp32 (K-contig). Output qT bf16 [1024][16384].
__global__ __launch_bounds__(256) void gemm_q(
    const float* __restrict__ Wq, const float* __restrict__ V,
    const float* __restrict__ bias, unsigned short* __restrict__ qT)
{
  __shared__ unsigned short As[BM * BK];
  __shared__ unsigned short Bs[BN * BK];

  const int m0 = blockIdx.y * BM;   // h tile
  const int n0 = blockIdx.x * BN;   // b*s tile
  const int t    = threadIdx.x;
  const int lane = t & 63;
  const int wave = t >> 6;
  const int wm = (wave >> 1) * 64;
  const int wn = (wave & 1) * 64;
  const int quad = lane >> 4;
  const int lrow = lane & 15;

  // staging: thread covers row sr, 16 consecutive K-elements at sc
  const int sr = t >> 1;            // 0..127
  const int sc = (t & 1) << 4;      // 0 or 16
  const float* gA = Wq + (size_t)(m0 + sr) * 1024 + sc;
  const float* gB = V  + (size_t)(n0 + sr) * 1024 + sc;

  f32x4 acc[4][4];
#pragma unroll
  for (int i = 0; i < 4; ++i)
#pragma unroll
    for (int j = 0; j < 4; ++j) acc[i][j] = (f32x4){0.f, 0.f, 0.f, 0.f};

  for (int k0 = 0; k0 < 1024; k0 += BK) {
    const float4* a4 = (const float4*)(gA + k0);
    const float4* b4 = (const float4*)(gB + k0);
    float4 av0 = a4[0], av1 = a4[1], av2 = a4[2], av3 = a4[3];
    float4 bv0 = b4[0], bv1 = b4[1], bv2 = b4[2], bv3 = b4[3];
    *(u16x8*)&As[sr * BK + sc]     = pack8(av0, av1);
    *(u16x8*)&As[sr * BK + sc + 8] = pack8(av2, av3);
    *(u16x8*)&Bs[sr * BK + sc]     = pack8(bv0, bv1);
    *(u16x8*)&Bs[sr * BK + sc + 8] = pack8(bv2, bv3);
    __syncthreads();

    bf16x8 af[4], bfr[4];
#pragma unroll
    for (int i = 0; i < 4; ++i)
      af[i] = *(const bf16x8*)&As[(wm + i * 16 + lrow) * BK + quad * 8];
#pragma unroll
    for (int j = 0; j < 4; ++j)
      bfr[j] = *(const bf16x8*)&Bs[(wn + j * 16 + lrow) * BK + quad * 8];
#pragma unroll
    for (int i = 0; i < 4; ++i)
#pragma unroll
      for (int j = 0; j < 4; ++j)
        acc[i][j] = __builtin_amdgcn_mfma_f32_16x16x32_bf16(af[i], bfr[j], acc[i][j], 0, 0, 0);
    __syncthreads();
  }

  // epilogue: C row = h (m), col = n (b*s). row = quad*4+reg, col = lrow (per 16-tile)
#pragma unroll
  for (int i = 0; i < 4; ++i) {
    const int mb = m0 + wm + i * 16 + quad * 4;
#pragma unroll
    for (int r = 0; r < 4; ++r) {
      const float bv = bias[mb + r];
#pragma unroll
      for (int j = 0; j < 4; ++j) {
        const int n = n0 + wn + j * 16 + lrow;
        qT[(size_t)(mb + r) * 16384 + n] = f2bf(acc[i][j][r] + bv);
      }
    }
  }
}

// ---------------- Kernel B: per-batch C = qb qb^T (x,y), fused relu+dot ----------------
// qT bf16 [1024][16384]; batch bb uses columns [bb*2048, bb*2048+2048).
__global__ __launch_bounds__(256) void syrk_dot(
    const unsigned short* __restrict__ qT, const float* __restrict__ W,
    float* __restrict__ out)
{
  __shared__ unsigned short As[BM * BK];
  __shared__ unsigned short Bs[BN * BK];

  const int bb = blockIdx.z;
  const int x0 = blockIdx.y * BM;
  const int y0 = blockIdx.x * BN;
  const int t    = threadIdx.x;
  const int lane = t & 63;
  const int wave = t >> 6;
  const int wm = (wave >> 1) * 64;
  const int wn = (wave & 1) * 64;
  const int quad = lane >> 4;
  const int lrow = lane & 15;

  // global_load_lds staging: issue p covers rows p*64 + t/4, cols (t&3)*8
  const int arow = t >> 2;          // 0..63
  const int acol = (t & 3) << 3;    // 0,8,16,24
  const size_t cbase = (size_t)bb * 2048 + acol;
  const unsigned short* gA0 = qT + (size_t)(x0 + arow) * 16384 + cbase;
  const unsigned short* gA1 = qT + (size_t)(x0 + 64 + arow) * 16384 + cbase;
  const unsigned short* gB0 = qT + (size_t)(y0 + arow) * 16384 + cbase;
  const unsigned short* gB1 = qT + (size_t)(y0 + 64 + arow) * 16384 + cbase;

  f32x4 acc[4][4];
#pragma unroll
  for (int i = 0; i < 4; ++i)
#pragma unroll
    for (int j = 0; j < 4; ++j) acc[i][j] = (f32x4){0.f, 0.f, 0.f, 0.f};

  for (int k0 = 0; k0 < 2048; k0 += BK) {
    async16(&As[t * 8],        gA0 + k0);
    async16(&As[2048 + t * 8], gA1 + k0);
    async16(&Bs[t * 8],        gB0 + k0);
    async16(&Bs[2048 + t * 8], gB1 + k0);
    __syncthreads();   // drains vmcnt (global_load_lds) + makes LDS visible

    bf16x8 af[4], bfr[4];
#pragma unroll
    for (int i = 0; i < 4; ++i)
      af[i] = *(const bf16x8*)&As[(wm + i * 16 + lrow) * BK + quad * 8];
#pragma unroll
    for (int j = 0; j < 4; ++j)
      bfr[j] = *(const bf16x8*)&Bs[(wn + j * 16 + lrow) * BK + quad * 8];
#pragma unroll
    for (int i = 0; i < 4; ++i)
#pragma unroll
      for (int j = 0; j < 4; ++j)
        acc[i][j] = __builtin_amdgcn_mfma_f32_16x16x32_bf16(af[i], bfr[j], acc[i][j], 0, 0, 0);
    __syncthreads();
  }

  // epilogue: out[bb, x] += sum_y relu(C[x][y]) * W[y]
  float wv[4];
#pragma unroll
  for (int j = 0; j < 4; ++j) wv[j] = W[y0 + wn + j * 16 + lrow];

#pragma unroll
  for (int i = 0; i < 4; ++i) {
#pragma unroll
    for (int r = 0; r < 4; ++r) {
      float p = 0.f;
#pragma unroll
      for (int j = 0; j < 4; ++j) {
        float v = acc[i][j][r];
        v = v > 0.f ? v : 0.f;
        p += v * wv[j];
      }
      // reduce over the 16 column-lanes within each quad
#pragma unroll
      for (int off = 1; off < 16; off <<= 1) p += __shfl_xor(p, off, 64);
      if (lrow == 0) {
        const int x = x0 + wm + i * 16 + quad * 4 + r;
        atomicAdd(&out[bb * 1024 + x], p);
      }
    }
  }
}

extern "C" void kernel_launch(void* const* d_in, const int* in_sizes, int n_in,
                              void* d_out, int out_size, void* d_ws, size_t ws_size,
                              hipStream_t stream) {
  const float* vec   = (const float*)d_in[0];  // [8,2048,1024]
  const float* wq_w  = (const float*)d_in[1];  // [1024,1024]
  const float* wq_b  = (const float*)d_in[2];  // [1024]
  const float* lin_w = (const float*)d_in[3];  // [1,1024]
  const float* lin_b = (const float*)d_in[4];  // [1]
  float* out = (float*)d_out;                  // [8,1024]
  unsigned short* qT = (unsigned short*)d_ws;  // bf16 [1024][16384] = 32 MiB

  init_out<<<dim3(32), dim3(256), 0, stream>>>(out, lin_b);
  gemm_q<<<dim3(128, 8), dim3(256), 0, stream>>>(wq_w, vec, wq_b, qT);
  syrk_dot<<<dim3(8, 8, 8), dim3(256), 0, stream>>>(qT, lin_w, out);
}

// Round 2
// 192.228 us; speedup vs baseline: 1.2916x; 1.2916x over previous
//
#include <hip/hip_runtime.h>

// B=8, S=2048, IN=1024, H=1024
//   q  = vec @ wq_w^T + wq_b            [B,S,H]
//   ret= relu(q_b^T q_b) per batch      [B,H,H]   (registers only)
//   out= ret @ lin_w + lin_b            [B,H]
//
// Pipeline: cvt(vec,wq -> bf16) ; gemm_q (m97-style global_load_lds) -> qT bf16
//           syrk_dot (BK=64, swizzled LDS) with fused relu+dot epilogue.

#define BM 128
#define BN 128

typedef short     bf16x8 __attribute__((ext_vector_type(8)));
typedef unsigned short u16x8 __attribute__((ext_vector_type(8)));
typedef float     f32x4 __attribute__((ext_vector_type(4)));

__device__ inline unsigned short f2bf(float f) {
  unsigned int u = __float_as_uint(f);
  u += 0x7fffu + ((u >> 16) & 1u);   // RNE
  return (unsigned short)(u >> 16);
}

__device__ inline u16x8 pack8(float4 a, float4 b) {
  u16x8 r;
  r[0] = f2bf(a.x); r[1] = f2bf(a.y); r[2] = f2bf(a.z); r[3] = f2bf(a.w);
  r[4] = f2bf(b.x); r[5] = f2bf(b.y); r[6] = f2bf(b.z); r[7] = f2bf(b.w);
  return r;
}

__device__ inline void async16(unsigned short* lds, const unsigned short* g) {
  __builtin_amdgcn_global_load_lds(
      (const __attribute__((address_space(1))) void*)g,
      (__attribute__((address_space(3))) void*)lds,
      16, 0, 0);
}

__global__ void init_out(float* __restrict__ out, const float* __restrict__ lin_b) {
  int i = blockIdx.x * 256 + threadIdx.x;
  if (i < 8192) out[i] = lin_b[0];
}

// fp32 -> bf16, 8 elements/thread
__global__ __launch_bounds__(256) void cvt_bf16(
    const float* __restrict__ src, unsigned short* __restrict__ dst, int n8)
{
  int i = blockIdx.x * 256 + threadIdx.x;
  if (i < n8) {
    const float4* s = (const float4*)(src + (size_t)i * 8);
    float4 a = s[0], b = s[1];
    *(u16x8*)(dst + (size_t)i * 8) = pack8(a, b);
  }
}

// ---------------- gemm_q (m97-style): qT = wqbf * vecbf^T + bias ----------------
// A=wqbf [1024,1024] bf16 K-contig, B=vecbf [16384,1024] bf16 K-contig.
// Output qT bf16 [1024][16384]. BK=32, 128x128 tile, XOR-swizzled LDS chunks.
__global__ __launch_bounds__(256) void gemm_q(
    const unsigned short* __restrict__ A, const unsigned short* __restrict__ Bm,
    const float* __restrict__ bias, unsigned short* __restrict__ qT)
{
  __shared__ unsigned short As[BM * 32];
  __shared__ unsigned short Bs[BN * 32];

  const int m0 = blockIdx.y * BM;
  const int n0 = blockIdx.x * BN;
  const int t    = threadIdx.x;
  const int lane = t & 63;
  const int wave = t >> 6;
  const int wm = (wave >> 1) * 64;
  const int wn = (wave & 1) * 64;
  const int quad = lane >> 4;
  const int lrow = lane & 15;

  // staging: issue p covers rows p*64 + (t>>2); global chunk XOR-swizzled
  const int srow = t >> 2;                               // 0..63
  const int gcol = (((t & 3) ^ ((srow >> 1) & 3)) << 3); // swizzled col (shorts)
  const unsigned short* gA0 = A  + (size_t)(m0 + srow) * 1024 + gcol;
  const unsigned short* gA1 = gA0 + (size_t)64 * 1024;
  const unsigned short* gB0 = Bm + (size_t)(n0 + srow) * 1024 + gcol;
  const unsigned short* gB1 = gB0 + (size_t)64 * 1024;

  // ds_read chunk index (swizzle inverse), independent of i
  const int rc = (quad ^ ((lrow >> 1) & 3)) << 3;        // shorts

  f32x4 acc[4][4];
#pragma unroll
  for (int i = 0; i < 4; ++i)
#pragma unroll
    for (int j = 0; j < 4; ++j) acc[i][j] = (f32x4){0.f, 0.f, 0.f, 0.f};

  for (int k0 = 0; k0 < 1024; k0 += 32) {
    async16(&As[t * 8],        gA0 + k0);
    async16(&As[2048 + t * 8], gA1 + k0);
    async16(&Bs[t * 8],        gB0 + k0);
    async16(&Bs[2048 + t * 8], gB1 + k0);
    __syncthreads();

    bf16x8 af[4], bfr[4];
#pragma unroll
    for (int i = 0; i < 4; ++i)
      af[i] = *(const bf16x8*)&As[(wm + i * 16 + lrow) * 32 + rc];
#pragma unroll
    for (int j = 0; j < 4; ++j)
      bfr[j] = *(const bf16x8*)&Bs[(wn + j * 16 + lrow) * 32 + rc];
#pragma unroll
    for (int i = 0; i < 4; ++i)
#pragma unroll
      for (int j = 0; j < 4; ++j)
        acc[i][j] = __builtin_amdgcn_mfma_f32_16x16x32_bf16(af[i], bfr[j], acc[i][j], 0, 0, 0);
    __syncthreads();
  }

#pragma unroll
  for (int i = 0; i < 4; ++i) {
    const int mb = m0 + wm + i * 16 + quad * 4;
#pragma unroll
    for (int r = 0; r < 4; ++r) {
      const float bv = bias[mb + r];
#pragma unroll
      for (int j = 0; j < 4; ++j) {
        const int n = n0 + wn + j * 16 + lrow;
        qT[(size_t)(mb + r) * 16384 + n] = f2bf(acc[i][j][r] + bv);
      }
    }
  }
}

// ------- fallback gemm_q (fused fp32->bf16 inline), used if ws too small -------
__global__ __launch_bounds__(256) void gemm_q_fused(
    const float* __restrict__ Wq, const float* __restrict__ V,
    const float* __restrict__ bias, unsigned short* __restrict__ qT)
{
  __shared__ unsigned short As[BM * 32];
  __shared__ unsigned short Bs[BN * 32];

  const int m0 = blockIdx.y * BM;
  const int n0 = blockIdx.x * BN;
  const int t    = threadIdx.x;
  const int lane = t & 63;
  const int wave = t >> 6;
  const int wm = (wave >> 1) * 64;
  const int wn = (wave & 1) * 64;
  const int quad = lane >> 4;
  const int lrow = lane & 15;

  const int sr = t >> 1;
  const int sc = (t & 1) << 4;
  const float* gA = Wq + (size_t)(m0 + sr) * 1024 + sc;
  const float* gB = V  + (size_t)(n0 + sr) * 1024 + sc;

  f32x4 acc[4][4];
#pragma unroll
  for (int i = 0; i < 4; ++i)
#pragma unroll
    for (int j = 0; j < 4; ++j) acc[i][j] = (f32x4){0.f, 0.f, 0.f, 0.f};

  for (int k0 = 0; k0 < 1024; k0 += 32) {
    const float4* a4 = (const float4*)(gA + k0);
    const float4* b4 = (const float4*)(gB + k0);
    float4 av0 = a4[0], av1 = a4[1], av2 = a4[2], av3 = a4[3];
    float4 bv0 = b4[0], bv1 = b4[1], bv2 = b4[2], bv3 = b4[3];
    *(u16x8*)&As[sr * 32 + sc]     = pack8(av0, av1);
    *(u16x8*)&As[sr * 32 + sc + 8] = pack8(av2, av3);
    *(u16x8*)&Bs[sr * 32 + sc]     = pack8(bv0, bv1);
    *(u16x8*)&Bs[sr * 32 + sc + 8] = pack8(bv2, bv3);
    __syncthreads();

    bf16x8 af[4], bfr[4];
#pragma unroll
    for (int i = 0; i < 4; ++i)
      af[i] = *(const bf16x8*)&As[(wm + i * 16 + lrow) * 32 + quad * 8];
#pragma unroll
    for (int j = 0; j < 4; ++j)
      bfr[j] = *(const bf16x8*)&Bs[(wn + j * 16 + lrow) * 32 + quad * 8];
#pragma unroll
    for (int i = 0; i < 4; ++i)
#pragma unroll
      for (int j = 0; j < 4; ++j)
        acc[i][j] = __builtin_amdgcn_mfma_f32_16x16x32_bf16(af[i], bfr[j], acc[i][j], 0, 0, 0);
    __syncthreads();
  }

#pragma unroll
  for (int i = 0; i < 4; ++i) {
    const int mb = m0 + wm + i * 16 + quad * 4;
#pragma unroll
    for (int r = 0; r < 4; ++r) {
      const float bv = bias[mb + r];
#pragma unroll
      for (int j = 0; j < 4; ++j) {
        const int n = n0 + wn + j * 16 + lrow;
        qT[(size_t)(mb + r) * 16384 + n] = f2bf(acc[i][j][r] + bv);
      }
    }
  }
}

// ---------------- syrk_dot: per-batch C = qb qb^T, fused relu+dot ----------------
// BK=64 (half the barriers), XOR-swizzled LDS chunks (conflict-free reads).
__global__ __launch_bounds__(256) void syrk_dot(
    const unsigned short* __restrict__ qT, const float* __restrict__ W,
    float* __restrict__ out)
{
  __shared__ unsigned short As[BM * 64];
  __shared__ unsigned short Bs[BN * 64];

  const int bb = blockIdx.z;
  const int x0 = blockIdx.y * BM;
  const int y0 = blockIdx.x * BN;
  const int t    = threadIdx.x;
  const int lane = t & 63;
  const int wave = t >> 6;
  const int wm = (wave >> 1) * 64;
  const int wn = (wave & 1) * 64;
  const int quad = lane >> 4;
  const int lrow = lane & 15;

  // staging: issue p covers rows p*32 + (t>>3); global chunk XOR-swizzled
  const int srow = t >> 3;                              // 0..31
  const int gcol = (((t & 7) ^ (srow & 7)) << 3);       // shorts
  const size_t cbase = (size_t)bb * 2048 + gcol;
  const unsigned short* gA = qT + (size_t)(x0 + srow) * 16384 + cbase;
  const unsigned short* gB = qT + (size_t)(y0 + srow) * 16384 + cbase;

  f32x4 acc[4][4];
#pragma unroll
  for (int i = 0; i < 4; ++i)
#pragma unroll
    for (int j = 0; j < 4; ++j) acc[i][j] = (f32x4){0.f, 0.f, 0.f, 0.f};

  for (int k0 = 0; k0 < 2048; k0 += 64) {
#pragma unroll
    for (int p = 0; p < 4; ++p) {
      async16(&As[p * 2048 + t * 8], gA + (size_t)p * 32 * 16384 + k0);
      async16(&Bs[p * 2048 + t * 8], gB + (size_t)p * 32 * 16384 + k0);
    }
    __syncthreads();

#pragma unroll
    for (int kk = 0; kk < 2; ++kk) {
      const int rc = (((kk * 4 + quad) ^ (lrow & 7)) << 3);  // shorts
      bf16x8 af[4], bfr[4];
#pragma unroll
      for (int i = 0; i < 4; ++i)
        af[i] = *(const bf16x8*)&As[(wm + i * 16 + lrow) * 64 + rc];
#pragma unroll
      for (int j = 0; j < 4; ++j)
        bfr[j] = *(const bf16x8*)&Bs[(wn + j * 16 + lrow) * 64 + rc];
#pragma unroll
      for (int i = 0; i < 4; ++i)
#pragma unroll
        for (int j = 0; j < 4; ++j)
          acc[i][j] = __builtin_amdgcn_mfma_f32_16x16x32_bf16(af[i], bfr[j], acc[i][j], 0, 0, 0);
    }
    __syncthreads();
  }

  // epilogue: out[bb, x] += sum_y relu(C[x][y]) * W[y]
  float wv[4];
#pragma unroll
  for (int j = 0; j < 4; ++j) wv[j] = W[y0 + wn + j * 16 + lrow];

#pragma unroll
  for (int i = 0; i < 4; ++i) {
#pragma unroll
    for (int r = 0; r < 4; ++r) {
      float p = 0.f;
#pragma unroll
      for (int j = 0; j < 4; ++j) {
        float v = acc[i][j][r];
        v = v > 0.f ? v : 0.f;
        p += v * wv[j];
      }
#pragma unroll
      for (int off = 1; off < 16; off <<= 1) p += __shfl_xor(p, off, 64);
      if (lrow == 0) {
        const int x = x0 + wm + i * 16 + quad * 4 + r;
        atomicAdd(&out[bb * 1024 + x], p);
      }
    }
  }
}

extern "C" void kernel_launch(void* const* d_in, const int* in_sizes, int n_in,
                              void* d_out, int out_size, void* d_ws, size_t ws_size,
                              hipStream_t stream) {
  const float* vec   = (const float*)d_in[0];  // [8,2048,1024]
  const float* wq_w  = (const float*)d_in[1];  // [1024,1024]
  const float* wq_b  = (const float*)d_in[2];  // [1024]
  const float* lin_w = (const float*)d_in[3];  // [1,1024]
  const float* lin_b = (const float*)d_in[4];  // [1]
  float* out = (float*)d_out;                  // [8,1024]

  unsigned short* qT = (unsigned short*)d_ws;                    // 32 MiB
  const size_t need = (size_t)(32 + 32 + 2) * 1024 * 1024;

  init_out<<<dim3(32), dim3(256), 0, stream>>>(out, lin_b);

  if (ws_size >= need) {
    unsigned short* vecbf = qT + (size_t)16 * 1024 * 1024;       // 32 MiB
    unsigned short* wqbf  = vecbf + (size_t)16 * 1024 * 1024;    // 2 MiB
    cvt_bf16<<<dim3(8192), dim3(256), 0, stream>>>(vec,  vecbf, 16777216 / 8);
    cvt_bf16<<<dim3(512),  dim3(256), 0, stream>>>(wq_w, wqbf,  1048576 / 8);
    gemm_q<<<dim3(128, 8), dim3(256), 0, stream>>>(wqbf, vecbf, wq_b, qT);
  } else {
    gemm_q_fused<<<dim3(128, 8), dim3(256), 0, stream>>>(wq_w, vec, wq_b, qT);
  }
  syrk_dot<<<dim3(8, 8, 8), dim3(256), 0, stream>>>(qT, lin_w, out);
}